// Round 8
// baseline (474.095 us; speedup 1.0000x reference)
//
#include <hip/hip_runtime.h>

// PMF rating prediction: out[p] = relu(dot(U[user_ids[p]], V[item_ids[p]])), D=64.
//
// Architecture: counting sort of pairs into 1024 user-id-range buckets
// (hist -> scans -> scatter), then ONE fused block per WHOLE bucket that
// sub-sorts its contiguous segment into LDS at 8-user granularity and
// computes from LDS.
//
// R8 (from R7 counters): half-bucket split sent ~50% of repeat touches to a
// different CU -> FETCH 403MB (predicted 300). Whole-bucket-per-block makes
// every repeat same-block/same-CU by construction: fetch model
// users ~225 + items ~30 + recs 32 ~= 290-310MB. 1024 buckets of 1024 users
// keep LDS at 22.5KB (grid 1024 -> 4 blocks/CU, ~50% occ).
// No global atomics anywhere; all blocks <=512 threads.

constexpr int HIDDEN = 64;
constexpr int K = 4;               // pairs per 16-lane group (fallback kernel)
constexpr int NBUCK = 1024;        // user-id range buckets
constexpr int MAX_CHUNKS = 512;    // max sort chunks
constexpr int BASE_CHUNK = 4096;   // pairs per sort chunk (grows if n large)
constexpr int SUBB = 128;          // sub-buckets per bucket (8-user bins)
constexpr int MAXSEG = 2560;       // max records LDS-sortable per bucket

using uint = unsigned int;
using u64 = unsigned long long;

// ---------------------------------------------------------------------------
// Fallback: round-0 kernel (419us harness), used when ws/shape doesn't fit.
// ---------------------------------------------------------------------------
__global__ __launch_bounds__(256) void pmf_dot_kernel(
    const float* __restrict__ user_emb,
    const float* __restrict__ item_emb,
    const int*   __restrict__ user_ids,
    const int*   __restrict__ item_ids,
    float*       __restrict__ out,
    int n_pairs)
{
    const int group  = (blockIdx.x * blockDim.x + threadIdx.x) >> 4;
    const int lane16 = threadIdx.x & 15;
    const int p0     = group * K;

    if (p0 + K <= n_pairs) {
        const int4 u4 = *reinterpret_cast<const int4*>(user_ids + p0);
        const int4 i4 = *reinterpret_cast<const int4*>(item_ids + p0);

        const float4* up0 = reinterpret_cast<const float4*>(user_emb + (size_t)u4.x * HIDDEN) + lane16;
        const float4* up1 = reinterpret_cast<const float4*>(user_emb + (size_t)u4.y * HIDDEN) + lane16;
        const float4* up2 = reinterpret_cast<const float4*>(user_emb + (size_t)u4.z * HIDDEN) + lane16;
        const float4* up3 = reinterpret_cast<const float4*>(user_emb + (size_t)u4.w * HIDDEN) + lane16;
        const float4* vp0 = reinterpret_cast<const float4*>(item_emb + (size_t)i4.x * HIDDEN) + lane16;
        const float4* vp1 = reinterpret_cast<const float4*>(item_emb + (size_t)i4.y * HIDDEN) + lane16;
        const float4* vp2 = reinterpret_cast<const float4*>(item_emb + (size_t)i4.z * HIDDEN) + lane16;
        const float4* vp3 = reinterpret_cast<const float4*>(item_emb + (size_t)i4.w * HIDDEN) + lane16;

        const float4 a0 = *up0, a1 = *up1, a2 = *up2, a3 = *up3;
        const float4 b0 = *vp0, b1 = *vp1, b2 = *vp2, b3 = *vp3;

        float d0 = a0.x * b0.x + a0.y * b0.y + a0.z * b0.z + a0.w * b0.w;
        float d1 = a1.x * b1.x + a1.y * b1.y + a1.z * b1.z + a1.w * b1.w;
        float d2 = a2.x * b2.x + a2.y * b2.y + a2.z * b2.z + a2.w * b2.w;
        float d3 = a3.x * b3.x + a3.y * b3.y + a3.z * b3.z + a3.w * b3.w;

        #pragma unroll
        for (int s = 1; s < 16; s <<= 1) {
            d0 += __shfl_xor(d0, s, 16);
            d1 += __shfl_xor(d1, s, 16);
            d2 += __shfl_xor(d2, s, 16);
            d3 += __shfl_xor(d3, s, 16);
        }

        if (lane16 == 0) {
            float4 r;
            r.x = d0 > 0.0f ? d0 : 0.0f;
            r.y = d1 > 0.0f ? d1 : 0.0f;
            r.z = d2 > 0.0f ? d2 : 0.0f;
            r.w = d3 > 0.0f ? d3 : 0.0f;
            *reinterpret_cast<float4*>(out + p0) = r;
        }
    } else if (p0 < n_pairs) {
        for (int p = p0; p < n_pairs; ++p) {
            const int uid = user_ids[p];
            const int iid = item_ids[p];
            const float4 a = *(reinterpret_cast<const float4*>(user_emb + (size_t)uid * HIDDEN) + lane16);
            const float4 b = *(reinterpret_cast<const float4*>(item_emb + (size_t)iid * HIDDEN) + lane16);
            float d = a.x * b.x + a.y * b.y + a.z * b.z + a.w * b.w;
            #pragma unroll
            for (int s = 1; s < 16; s <<= 1) d += __shfl_xor(d, s, 16);
            if (lane16 == 0) out[p] = d > 0.0f ? d : 0.0f;
        }
    }
}

// ---------------------------------------------------------------------------
// Pass A: per-chunk bucket histogram (1024 buckets). LDS counters only,
// int4 vector id loads, coalesced plain store of the counts.
// ---------------------------------------------------------------------------
__global__ __launch_bounds__(256) void chunk_hist_kernel(
    const int* __restrict__ uids, uint* __restrict__ chunkhist,
    int n, int chunk, int shift)
{
    __shared__ uint h[NBUCK];
    for (int i = threadIdx.x; i < NBUCK; i += 256) h[i] = 0u;
    __syncthreads();
    const int start = blockIdx.x * chunk;
    const int end   = min(start + chunk, n);
    const int L     = end - start;
    const int L4    = L & ~3;
    for (int i = start + threadIdx.x * 4; i < start + L4; i += 1024) {
        const int4 u4 = *reinterpret_cast<const int4*>(uids + i);
        atomicAdd(&h[min(((uint)u4.x) >> shift, (uint)(NBUCK - 1))], 1u);
        atomicAdd(&h[min(((uint)u4.y) >> shift, (uint)(NBUCK - 1))], 1u);
        atomicAdd(&h[min(((uint)u4.z) >> shift, (uint)(NBUCK - 1))], 1u);
        atomicAdd(&h[min(((uint)u4.w) >> shift, (uint)(NBUCK - 1))], 1u);
    }
    for (int i = start + L4 + threadIdx.x; i < end; i += 256)
        atomicAdd(&h[min(((uint)uids[i]) >> shift, (uint)(NBUCK - 1))], 1u);
    __syncthreads();
    for (int i = threadIdx.x; i < NBUCK; i += 256)
        chunkhist[(size_t)blockIdx.x * NBUCK + i] = h[i];
}

// ---------------------------------------------------------------------------
// Pass B1: parallel per-bucket prefix over chunks. Block b handles bucket b
// (1024 blocks x 512 threads; thread t owns chunk t).
// ---------------------------------------------------------------------------
__global__ __launch_bounds__(MAX_CHUNKS) void scanB1_kernel(
    const uint* __restrict__ chunkhist, uint* __restrict__ chunkbase,
    uint* __restrict__ btotal, int nchunks)
{
    __shared__ uint tmp[MAX_CHUNKS];
    const int b = blockIdx.x;
    const int t = threadIdx.x;
    const uint v = (t < nchunks) ? chunkhist[(size_t)t * NBUCK + b] : 0u;
    tmp[t] = v;
    __syncthreads();
    #pragma unroll
    for (int d = 1; d < MAX_CHUNKS; d <<= 1) {
        const uint w = (t >= d) ? tmp[t - d] : 0u;
        __syncthreads();
        tmp[t] += w;
        __syncthreads();
    }
    if (t < nchunks)
        chunkbase[(size_t)t * NBUCK + b] = tmp[t] - v;  // exclusive, no start
    if (t == MAX_CHUNKS - 1) btotal[b] = tmp[t];
}

// ---------------------------------------------------------------------------
// Pass B2: one 512-thread block scans 1024 bucket totals (2 elems/thread)
// -> offsets[1025].
// ---------------------------------------------------------------------------
__global__ __launch_bounds__(512) void scanB2_kernel(
    const uint* __restrict__ btotal, uint* __restrict__ offsets)
{
    __shared__ uint ps[512];
    const int t = threadIdx.x;
    const uint a = btotal[2 * t];
    const uint b = btotal[2 * t + 1];
    ps[t] = a + b;
    __syncthreads();
    #pragma unroll
    for (int d = 1; d < 512; d <<= 1) {
        const uint w = (t >= d) ? ps[t - d] : 0u;
        __syncthreads();
        ps[t] += w;
        __syncthreads();
    }
    const uint excl = t ? ps[t - 1] : 0u;   // exclusive over pair-sums
    offsets[2 * t]     = excl;
    offsets[2 * t + 1] = excl + a;
    if (t == 511) offsets[NBUCK] = ps[511];
}

// ---------------------------------------------------------------------------
// Pass C: scatter into bucket order as packed 8B records
// rec = uid | iid<<bits_u | pair_idx<<(bits_u+bits_i). LDS atomics only;
// int4 vector id loads.
// ---------------------------------------------------------------------------
__global__ __launch_bounds__(256) void scatter_kernel(
    const int* __restrict__ uids, const int* __restrict__ iids,
    const uint* __restrict__ chunkbase, const uint* __restrict__ offsets,
    u64* __restrict__ recs, int n, int chunk, int shift, int bits_u, int bits_i)
{
    __shared__ uint base[NBUCK];
    __shared__ uint lcnt[NBUCK];
    for (int i = threadIdx.x; i < NBUCK; i += 256) {
        base[i] = chunkbase[(size_t)blockIdx.x * NBUCK + i] + offsets[i];
        lcnt[i] = 0u;
    }
    __syncthreads();
    const int start = blockIdx.x * chunk;
    const int end   = min(start + chunk, n);
    const int L     = end - start;
    const int L4    = L & ~3;
    for (int i = start + threadIdx.x * 4; i < start + L4; i += 1024) {
        const int4 u4 = *reinterpret_cast<const int4*>(uids + i);
        const int4 i4 = *reinterpret_cast<const int4*>(iids + i);
        const int us[4] = {u4.x, u4.y, u4.z, u4.w};
        const int vs[4] = {i4.x, i4.y, i4.z, i4.w};
        #pragma unroll
        for (int k = 0; k < 4; ++k) {
            const uint u = (uint)us[k];
            const uint b = min(u >> shift, (uint)(NBUCK - 1));
            const uint slot = base[b] + atomicAdd(&lcnt[b], 1u);  // LDS atomic
            if (slot < (uint)n)
                recs[slot] = (u64)u | ((u64)(uint)vs[k] << bits_u)
                           | ((u64)(uint)(i + k) << (bits_u + bits_i));
        }
    }
    for (int i = start + L4 + threadIdx.x; i < end; i += 256) {
        const uint u = (uint)uids[i];
        const uint b = min(u >> shift, (uint)(NBUCK - 1));
        const uint slot = base[b] + atomicAdd(&lcnt[b], 1u);
        if (slot < (uint)n)
            recs[slot] = (u64)u | ((u64)(uint)iids[i] << bits_u)
                       | ((u64)(uint)i << (bits_u + bits_i));
    }
}

// ---------------------------------------------------------------------------
// Pass D (fused sub-sort + compute): ONE block per WHOLE bucket (~1950 recs).
// Sweep 1: histogram 128 sub-buckets (8-user bins). LDS scan. Sweep 2:
// re-read (L1/L2-hot) and place sorted records in LDS. Compute from LDS:
// ALL touches of a user row occur on THIS CU within a ~16-record window ->
// L1/MSHR-merged -> each user row HBM-fetched once. Segments > MAXSEG
// (adversarial only) compute unsorted from global: correct, just slower.
// use_lds is block-uniform (no divergent barriers).
// ---------------------------------------------------------------------------
__global__ __launch_bounds__(256) void pmf_fused_kernel(
    const float* __restrict__ user_emb,
    const float* __restrict__ item_emb,
    const uint*  __restrict__ offsets,
    const u64*   __restrict__ recs,
    float*       __restrict__ out,
    int bits_u, int bits_i, int subshift)
{
    __shared__ u64  lrec[MAXSEG];
    __shared__ uint h[SUBB];
    __shared__ uint tmp[SUBB];
    __shared__ uint sbase[SUBB];
    __shared__ uint scnt[SUBB];

    const uint s = offsets[blockIdx.x];
    const uint e = offsets[blockIdx.x + 1];
    const uint len = (e > s) ? (e - s) : 0u;

    const int t = threadIdx.x;
    const u64 mu = ((u64)1 << bits_u) - 1;
    const u64 mi = ((u64)1 << bits_i) - 1;

    const bool use_lds = (len > 0u) && (len <= (uint)MAXSEG);
    if (use_lds) {
        if (t < SUBB) h[t] = 0u;
        __syncthreads();
        for (uint i = (uint)t; i < len; i += 256u) {
            const uint uid = (uint)(recs[s + i] & mu);
            atomicAdd(&h[(uid >> subshift) & (SUBB - 1)], 1u);
        }
        __syncthreads();
        const uint v = (t < SUBB) ? h[t] : 0u;
        if (t < SUBB) tmp[t] = v;
        __syncthreads();
        #pragma unroll
        for (int d = 1; d < SUBB; d <<= 1) {
            uint w = 0u;
            if (t < SUBB && t >= d) w = tmp[t - d];
            __syncthreads();
            if (t < SUBB) tmp[t] += w;
            __syncthreads();
        }
        if (t < SUBB) { sbase[t] = tmp[t] - v; scnt[t] = 0u; }
        __syncthreads();
        for (uint i = (uint)t; i < len; i += 256u) {
            const u64 r = recs[s + i];              // L1/L2-hot re-read
            const uint sb = ((uint)(r & mu) >> subshift) & (SUBB - 1);
            const uint dst = sbase[sb] + atomicAdd(&scnt[sb], 1u);  // LDS atomic
            if (dst < (uint)MAXSEG)                  // always true
                lrec[dst] = r;
        }
        __syncthreads();
    }

    const int lane16 = t & 15;
    const int g = t >> 4;   // 0..15 groups of 16 lanes, K=4 pairs each

    for (uint q = (uint)g * 4u; q < len; q += 64u) {
        uint idx = q + (uint)(lane16 & 3);
        if (idx >= len) idx = len - 1u;   // clamp; masked at store
        const u64 rec = use_lds ? lrec[idx] : recs[s + idx];
        const int uu = (int)(rec & mu);
        const int vv = (int)((rec >> bits_u) & mi);

        const int u0 = __shfl(uu, 0, 16), i0 = __shfl(vv, 0, 16);
        const int u1 = __shfl(uu, 1, 16), i1 = __shfl(vv, 1, 16);
        const int u2 = __shfl(uu, 2, 16), i2 = __shfl(vv, 2, 16);
        const int u3 = __shfl(uu, 3, 16), i3 = __shfl(vv, 3, 16);

        const float4* up0 = reinterpret_cast<const float4*>(user_emb + (size_t)u0 * HIDDEN) + lane16;
        const float4* up1 = reinterpret_cast<const float4*>(user_emb + (size_t)u1 * HIDDEN) + lane16;
        const float4* up2 = reinterpret_cast<const float4*>(user_emb + (size_t)u2 * HIDDEN) + lane16;
        const float4* up3 = reinterpret_cast<const float4*>(user_emb + (size_t)u3 * HIDDEN) + lane16;
        const float4* vp0 = reinterpret_cast<const float4*>(item_emb + (size_t)i0 * HIDDEN) + lane16;
        const float4* vp1 = reinterpret_cast<const float4*>(item_emb + (size_t)i1 * HIDDEN) + lane16;
        const float4* vp2 = reinterpret_cast<const float4*>(item_emb + (size_t)i2 * HIDDEN) + lane16;
        const float4* vp3 = reinterpret_cast<const float4*>(item_emb + (size_t)i3 * HIDDEN) + lane16;

        // Issue all 8 gathers before any use so they overlap.
        const float4 a0 = *up0, a1 = *up1, a2 = *up2, a3 = *up3;
        const float4 b0 = *vp0, b1 = *vp1, b2 = *vp2, b3 = *vp3;

        float d0 = a0.x * b0.x + a0.y * b0.y + a0.z * b0.z + a0.w * b0.w;
        float d1 = a1.x * b1.x + a1.y * b1.y + a1.z * b1.z + a1.w * b1.w;
        float d2 = a2.x * b2.x + a2.y * b2.y + a2.z * b2.z + a2.w * b2.w;
        float d3 = a3.x * b3.x + a3.y * b3.y + a3.z * b3.z + a3.w * b3.w;

        #pragma unroll
        for (int sft = 1; sft < 16; sft <<= 1) {
            d0 += __shfl_xor(d0, sft, 16);
            d1 += __shfl_xor(d1, sft, 16);
            d2 += __shfl_xor(d2, sft, 16);
            d3 += __shfl_xor(d3, sft, 16);
        }

        if (lane16 < 4 && (q + (uint)lane16) < len) {
            const float d = lane16 == 0 ? d0 : lane16 == 1 ? d1 : lane16 == 2 ? d2 : d3;
            out[(uint)(rec >> (bits_u + bits_i))] = d > 0.0f ? d : 0.0f;
        }
    }
}

// ---------------------------------------------------------------------------
extern "C" void kernel_launch(void* const* d_in, const int* in_sizes, int n_in,
                              void* d_out, int out_size, void* d_ws, size_t ws_size,
                              hipStream_t stream) {
    const float* user_emb = (const float*)d_in[0];
    const float* item_emb = (const float*)d_in[1];
    const int*   user_ids = (const int*)d_in[2];
    const int*   item_ids = (const int*)d_in[3];
    float* out = (float*)d_out;

    const int n_pairs = in_sizes[2];                 // 2,000,000

    // Shape-derived constants (bench: 1M users, 100K items, 2M pairs).
    const long long n_users = (long long)in_sizes[0] / HIDDEN;
    const long long n_items = (long long)in_sizes[1] / HIDDEN;

    // Bucket shift: 10 -> 1024 users/bucket covers uid < 1024*1024 = 1,048,576.
    // Kernels clamp the bucket index, so it is always in range regardless.
    int shift = 10;
    while (n_users > 0 && (((n_users - 1) >> shift) >= NBUCK)) ++shift;
    const int subshift = shift - 7;  // 128 sub-buckets of 2^(shift-7) users

    // Packed-record bit widths.
    auto bits_for = [](long long v) { int b = 1; while ((1ll << b) < v) ++b; return b; };
    const int bits_u = bits_for(n_users > 1 ? n_users : 2);
    const int bits_i = bits_for(n_items > 1 ? n_items : 2);
    const int bits_p = bits_for(n_pairs > 1 ? n_pairs : 2);

    // Chunk size: <= MAX_CHUNKS chunks.
    int chunk = BASE_CHUNK;
    while ((n_pairs + chunk - 1) / chunk > MAX_CHUNKS) chunk <<= 1;
    const int nchunks = (n_pairs + chunk - 1) / chunk;

    // Workspace layout (every word written before read in stream order):
    //   [0, 8192)            : offsets uint[1025] (+pad)
    //   [8192, 16384)        : btotal  uint[1024] (+pad)
    //   [16384, +2MB)        : chunkhist uint[512*1024]
    //   [+2MB, +4MB)         : chunkbase uint[512*1024]
    //   [+4MB, +4MB+8n)      : recs  u64[n_pairs]
    const size_t META = 16384 + 2ull * MAX_CHUNKS * NBUCK * sizeof(uint);
    const size_t ws_need = META + (size_t)n_pairs * sizeof(u64);

    const bool ok_shape = !(n_pairs < BASE_CHUNK || bits_u + bits_i + bits_p > 64 ||
                            n_users <= 0 || n_items <= 0 || subshift < 0);

    if (d_ws == nullptr || ws_size < ws_need || !ok_shape) {
        // Fallback: round-0 direct kernel.
        const int threads = 256;
        const int pairs_per_block = (threads / 16) * K;  // 64 pairs/block
        const int blocks = (n_pairs + pairs_per_block - 1) / pairs_per_block;
        pmf_dot_kernel<<<blocks, threads, 0, stream>>>(
            user_emb, item_emb, user_ids, item_ids, out, n_pairs);
        return;
    }

    uint* offsets   = (uint*)d_ws;                                   // [1025]
    uint* btotal    = (uint*)((char*)d_ws + 8192);                   // [1024]
    uint* chunkhist = (uint*)((char*)d_ws + 16384);                  // [512*1024]
    uint* chunkbase = chunkhist + (size_t)MAX_CHUNKS * NBUCK;        // [512*1024]
    u64*  recs      = (u64*)((char*)d_ws + META);                    // [n_pairs]

    chunk_hist_kernel<<<nchunks, 256, 0, stream>>>(
        user_ids, chunkhist, n_pairs, chunk, shift);
    scanB1_kernel<<<NBUCK, MAX_CHUNKS, 0, stream>>>(
        chunkhist, chunkbase, btotal, nchunks);
    scanB2_kernel<<<1, 512, 0, stream>>>(btotal, offsets);
    scatter_kernel<<<nchunks, 256, 0, stream>>>(
        user_ids, item_ids, chunkbase, offsets, recs, n_pairs, chunk, shift,
        bits_u, bits_i);
    pmf_fused_kernel<<<NBUCK, 256, 0, stream>>>(
        user_emb, item_emb, offsets, recs, out, bits_u, bits_i, subshift);
}